// Round 3
// baseline (245.014 us; speedup 1.0000x reference)
//
#include <hip/hip_runtime.h>
#include <math.h>

#define KTOT 69
#define NRADC 24
#define NFEAT 216
#define NELEMC 94
#define EMBC 16
#define H1C 256
#define H2C 128
#define CE 16          // edges per chunk in k_atom
#define EPR 20         // padded edge stride for s_radT rows
#define KGN 18         // padded k-groups (72 padded k / 4)
#define GSTR 84        // s_gijT kg-stride (4*20 + 4 pad -> spreads banks)
#define GISTR 76       // s_gi rad-stride

// ---- static lxlylz enumeration (z=1..4 concatenated; real k = 0..68) ----
__device__ __constant__ int c_lx[KTOT] = {
  0,0,0,1,
  0,0,0,1,0,0,0,1,1,2,
  0,0,0,1,0,0,0,1,1,2,0,0,0,0,1,1,1,2,2,3,
  0,0,0,1,0,0,0,1,1,2,0,0,0,0,1,1,1,2,2,3,0,0,0,0,0,1,1,1,1,2,2,2,3,3,4};
__device__ __constant__ int c_ly[KTOT] = {
  0,0,1,0,
  0,0,1,0,0,1,2,0,1,0,
  0,0,1,0,0,1,2,0,1,0,0,1,2,3,0,1,2,0,1,0,
  0,0,1,0,0,1,2,0,1,0,0,1,2,3,0,1,2,0,1,0,0,1,2,3,4,0,1,2,3,0,1,2,0,1,0};
__device__ __constant__ int c_lz[KTOT] = {
  0,1,0,0,
  0,1,0,0,2,1,0,1,0,0,
  0,1,0,0,2,1,0,1,0,0,3,2,1,0,2,1,0,1,0,0,
  0,1,0,0,2,1,0,1,0,0,3,2,1,0,2,1,0,1,0,0,4,3,2,1,0,3,2,1,0,2,1,0,1,0,0};
__device__ __constant__ float c_fn[KTOT] = {
  1,1,1,1,
  1,2,2,2,1,2,1,2,2,1,
  1,3,3,3,3,6,3,6,6,3,1,3,3,1,3,6,3,3,3,1,
  1,4,4,4,6,12,6,12,12,6,4,12,12,4,12,24,12,12,12,4,
  1,4,6,4,1,4,12,12,4,6,12,6,4,4,1};
__device__ __constant__ float c_lam[KTOT] = {
  1,-1,-1,-1,
  1,-1,-1,-1,1,1,1,1,1,1,
  1,-1,-1,-1,1,1,1,1,1,1,-1,-1,-1,-1,-1,-1,-1,-1,-1,-1,
  1,-1,-1,-1,1,1,1,1,1,1,-1,-1,-1,-1,-1,-1,-1,-1,-1,-1,
  1,1,1,1,1,1,1,1,1,1,1,1,1,1,1};
__device__ __constant__ int c_k0[4] = {0,4,14,34};
__device__ __constant__ int c_kn[4] = {4,10,20,35};
__device__ __constant__ float c_zn[4] = {1.0f, 0.5f, 0.25f, 0.125f};
// z per padded k-group (padded k layout: z0 rows 0-3, z1 4-15, z2 16-35, z3 36-71)
__device__ __constant__ int c_zidg[KGN] = {0, 1,1,1, 2,2,2,2,2, 3,3,3,3,3,3,3,3,3};

__device__ __forceinline__ float silu(float x) { return x / (1.0f + expf(-x)); }
__device__ __forceinline__ float4 silu4(float4 v) {
  v.x = silu(v.x); v.y = silu(v.y); v.z = silu(v.z); v.w = silu(v.w); return v;
}
__device__ __forceinline__ void fma4(float4& a, float s, const float4 w) {
  a.x += s * w.x; a.y += s * w.y; a.z += s * w.z; a.w += s * w.w;
}
__device__ __forceinline__ void fma44(float4& a, const float4 x, const float4 y) {
  a.x += x.x * y.x; a.y += x.y * y.y; a.z += x.z * y.z; a.w += x.w * y.w;
}
__device__ __forceinline__ float hsum4(const float4 v) { return (v.x + v.y) + (v.z + v.w); }
// p^l for l in 0..4 via cndmask chain (no indexed register array, no divergence)
__device__ __forceinline__ float powsel(int l, float p, float p2, float p3, float p4) {
  float v = 1.0f;
  v = l >= 1 ? p : v;
  v = l >= 2 ? p2 : v;
  v = l >= 3 ? p3 : v;
  v = l >= 4 ? p4 : v;
  return v;
}

// ---------------- Kernel 1: per-edge radial MLP (edge x ogroup parallel) ----
// radial output TRANSPOSED as float4: radial4[o4 * E + e], o4 in [0,30)
template <int NQ>
__device__ __forceinline__ void edge_layer2(
    const float* __restrict__ s_h, const float* __restrict__ Wr2,
    const float* __restrict__ br2, float4* __restrict__ radial4,
    int e, int og, int eg, int E) {
  float4 acc[NQ];
  const float4* b2 = (const float4*)(br2 + og * 32);
  #pragma unroll
  for (int q = 0; q < NQ; ++q) acc[q] = b2[q];
  #pragma unroll 2
  for (int j = 0; j < 64; ++j) {
    float hv = s_h[e * 65 + j];
    const float4* w = (const float4*)(Wr2 + j * 120 + og * 32);
    #pragma unroll
    for (int q = 0; q < NQ; ++q) fma4(acc[q], hv, w[q]);
  }
  if (eg < E) {
    #pragma unroll
    for (int q = 0; q < NQ; ++q)
      radial4[(size_t)(og * 8 + q) * E + eg] = silu4(acc[q]);
  }
}

__global__ __launch_bounds__(256) void k_edge(
    const float* __restrict__ rij,
    const float* __restrict__ Wr1, const float* __restrict__ br1,
    const float* __restrict__ Wr2, const float* __restrict__ br2,
    float4* __restrict__ radial4, int E) {
  __shared__ float s_bas[64 * 25];
  __shared__ float s_h[64 * 65];
  const int tid = threadIdx.x;
  const int e = tid & 63;
  const int og = __builtin_amdgcn_readfirstlane(tid >> 6);
  const int eg = blockIdx.x * 64 + e;

  {
    float x = 0.0f, y = 0.0f, z = 0.0f;
    if (eg < E) { x = rij[eg * 3 + 0]; y = rij[eg * 3 + 1]; z = rij[eg * 3 + 2]; }
    float r = sqrtf(x * x + y * y + z * z);
    float rc = fminf(r, 6.0f);
    float fcv = (eg < E)
        ? 0.5f * (cosf(3.14159265358979323846f * rc * (1.0f / 6.0f)) + 1.0f)
        : 0.0f;
    #pragma unroll
    for (int t = 0; t < 6; ++t) {
      int m = og * 6 + t;
      float d = r - (6.0f / 23.0f) * (float)m;
      s_bas[e * 25 + m] = expf(-8.0f * d * d) * fcv;
    }
  }
  __syncthreads();

  {
    const float4* b1 = (const float4*)(br1 + og * 16);
    float4 acc[4] = {b1[0], b1[1], b1[2], b1[3]};
    #pragma unroll 4
    for (int m = 0; m < NRADC; ++m) {
      float b = s_bas[e * 25 + m];
      const float4* w = (const float4*)(Wr1 + m * 64 + og * 16);
      #pragma unroll
      for (int q = 0; q < 4; ++q) fma4(acc[q], b, w[q]);
    }
    #pragma unroll
    for (int q = 0; q < 4; ++q) {
      float4 v = silu4(acc[q]);
      float* dst = &s_h[e * 65 + og * 16 + 4 * q];
      dst[0] = v.x; dst[1] = v.y; dst[2] = v.z; dst[3] = v.w;
    }
  }
  __syncthreads();

  if (og < 3) edge_layer2<8>(s_h, Wr2, br2, radial4, e, og, eg, E);
  else        edge_layer2<6>(s_h, Wr2, br2, radial4, e, og, eg, E);
}

// ---------------- Kernel 2: per-atom angular accumulation -> feat[216] ----
// v3: register-tiled outer product. 108 tiles (6 radgroups x 18 kgroups) x
// 2 edge-halves = 216 threads; each tile = 4 rads x 4 padded-ks, float4 accs
// over 4 edges. LDS:FMA = 8 b128 : 64 fma per step (was 2 b32 : 1 fma).
__global__ __launch_bounds__(256, 4) void k_atom(
    const float* __restrict__ rij,
    const float4* __restrict__ radial4,
    const int* __restrict__ fai,
    float* __restrict__ feat, int E) {
  const int a = blockIdx.x;
  const int tid = threadIdx.x;
  __shared__ __align__(16) float s_radT[120 * EPR];   // [comp][edge]
  __shared__ __align__(16) float s_gijT[KGN * GSTR];  // [kgroup][j*20+edge]
  __shared__ __align__(16) float s_gi[NRADC * GISTR]; // [rad][padded k]
  __shared__ float s_feat[NFEAT];

  // segment [start, end) via binary search
  int lo = 0, hi = E;
  while (lo < hi) { int mid = (lo + hi) >> 1; if (fai[mid] < a) lo = mid + 1; else hi = mid; }
  const int start = lo;
  hi = E;
  while (lo < hi) { int mid = (lo + hi) >> 1; if (fai[mid] < a + 1) lo = mid + 1; else hi = mid; }
  const int end = lo;

  // role assignment
  const bool is_tile = tid < 216;
  const int eh = is_tile ? (tid / 108) : 0;
  const int tile = is_tile ? (tid % 108) : 0;
  const int rg = tile % 6;
  const int kg = tile / 6;
  const int zz = c_zidg[kg];
  const int comp0 = rg * 20 + 1 + zz;   // (rg*4)*5 + 1 + z
  const bool is_2b = (tid >= 216 && tid < 240);
  const int rad2b = tid - 216;

  // zero the fake padded-k rows (prow 14,15,71), cols 0..19
  if (tid < 60) {
    int rr = tid / EPR, e = tid % EPR;
    int fkg = rr < 2 ? 3 : 17;
    int fj = rr < 2 ? 2 + rr : 3;
    s_gijT[fkg * GSTR + fj * EPR + e] = 0.0f;
  }

  float4 acc[4][4];
  #pragma unroll
  for (int i = 0; i < 4; ++i)
    #pragma unroll
    for (int j = 0; j < 4; ++j) acc[i][j] = make_float4(0, 0, 0, 0);
  float4 acc2b = make_float4(0, 0, 0, 0);

  for (int c0 = start; c0 < end; c0 += CE) {
    const int ne = min(CE, end - c0);
    // ---- stage radial transposed: [comp][e], zero for e >= ne ----
    for (int idx = tid; idx < 30 * CE; idx += 256) {
      int o4 = idx >> 4;
      int e = idx & 15;
      float4 v = make_float4(0, 0, 0, 0);
      if (e < ne) v = radial4[(size_t)o4 * E + (c0 + e)];
      int c = o4 * 4;
      s_radT[(c + 0) * EPR + e] = v.x;
      s_radT[(c + 1) * EPR + e] = v.y;
      s_radT[(c + 2) * EPR + e] = v.z;
      s_radT[(c + 3) * EPR + e] = v.w;
    }
    // ---- gij in registers -> s_gijT[kg][j*20+e] ----
    {
      int e = tid >> 4, sub = tid & 15;
      int eg = c0 + e;
      bool ev = e < ne;
      float x = 1.0f, y = 0.0f, z3 = 0.0f;
      if (ev) { x = rij[eg * 3 + 0]; y = rij[eg * 3 + 1]; z3 = rij[eg * 3 + 2]; }
      float r = sqrtf(x * x + y * y + z3 * z3);
      float inv = 1.0f / r;
      float px = x * inv + 1e-12f, py = y * inv + 1e-12f, pz = z3 * inv + 1e-12f;
      float p2x = px * px, p3x = p2x * px, p4x = p2x * p2x;
      float p2y = py * py, p3y = p2y * py, p4y = p2y * p2y;
      float p2z = pz * pz, p3z = p2z * pz, p4z = p2z * p2z;
      int kstart = sub < 5 ? sub * 5 : 25 + (sub - 5) * 4;
      int kcnt = sub < 5 ? 5 : 4;
      for (int t = 0; t < kcnt; ++t) {
        int k = kstart + t;
        float g = powsel(c_lx[k], px, p2x, p3x, p4x) *
                  powsel(c_ly[k], py, p2y, p3y, p4y) *
                  powsel(c_lz[k], pz, p2z, p3z, p4z) * c_fn[k];
        if (!ev) g = 0.0f;
        int prow = k + (k < 14 ? 0 : 2);
        s_gijT[(prow >> 2) * GSTR + (prow & 3) * EPR + e] = g;
      }
    }
    __syncthreads();
    // ---- tiled outer-product accumulate over 4-edge vectors ----
    if (is_tile) {
      #pragma unroll
      for (int s = 0; s < 2; ++s) {
        int e0 = eh * 8 + s * 4;
        float4 gg[4];
        #pragma unroll
        for (int j = 0; j < 4; ++j)
          gg[j] = *(const float4*)&s_gijT[kg * GSTR + j * EPR + e0];
        #pragma unroll
        for (int i = 0; i < 4; ++i) {
          float4 rr = *(const float4*)&s_radT[(comp0 + 5 * i) * EPR + e0];
          #pragma unroll
          for (int j = 0; j < 4; ++j) fma44(acc[i][j], rr, gg[j]);
        }
      }
    }
    if (is_2b) {
      #pragma unroll
      for (int e0 = 0; e0 < 16; e0 += 4) {
        float4 v = *(const float4*)&s_radT[(rad2b * 5) * EPR + e0];
        acc2b.x += v.x; acc2b.y += v.y; acc2b.z += v.z; acc2b.w += v.w;
      }
    }
    __syncthreads();
  }

  // ---- epilogue: horizontal sums -> s_gi, then cross-eh add ----
  float4 hs[4];
  #pragma unroll
  for (int i = 0; i < 4; ++i)
    hs[i] = make_float4(hsum4(acc[i][0]), hsum4(acc[i][1]),
                        hsum4(acc[i][2]), hsum4(acc[i][3]));
  if (is_tile && eh == 0) {
    #pragma unroll
    for (int i = 0; i < 4; ++i)
      *(float4*)&s_gi[(rg * 4 + i) * GISTR + kg * 4] = hs[i];
  }
  if (is_2b) s_feat[rad2b] = hsum4(acc2b);
  __syncthreads();
  if (is_tile && eh == 1) {
    #pragma unroll
    for (int i = 0; i < 4; ++i) {
      float4 v = *(const float4*)&s_gi[(rg * 4 + i) * GISTR + kg * 4];
      v.x += hs[i].x; v.y += hs[i].y; v.z += hs[i].z; v.w += hs[i].w;
      *(float4*)&s_gi[(rg * 4 + i) * GISTR + kg * 4] = v;
    }
  }
  __syncthreads();

  // ---- feat: sum g^2 (+/- lambda) over real ks ----
  if (tid < 192) {
    int zb = tid / NRADC;
    int rad = tid - zb * NRADC;
    int z = zb >> 1;
    bool neg = zb & 1;
    int k0 = c_k0[z], kn = c_kn[z];
    float s = 0.0f;
    for (int k = k0; k < k0 + kn; ++k) {
      int prow = k + (k < 14 ? 0 : 2);
      float g = s_gi[rad * GISTR + prow];
      float g2 = g * g;
      s += neg ? g2 * c_lam[k] : g2;
    }
    s_feat[NRADC + zb * NRADC + rad] = s * c_zn[z];
  }
  __syncthreads();
  if (tid < NFEAT) feat[(size_t)a * NFEAT + tid] = s_feat[tid];
}

// ---------------- species embedding (94 x 16) ----------------
__global__ void k_emb(const float* __restrict__ Ws1, const float* __restrict__ bs1,
                      const float* __restrict__ Ws2, const float* __restrict__ bs2,
                      float* __restrict__ emb) {
  int s = blockIdx.x, t = threadIdx.x;
  __shared__ float hh[32];
  if (t < 32) hh[t] = silu(Ws1[s * 32 + t] + bs1[t]);
  __syncthreads();
  if (t < EMBC) {
    float acc = bs2[t];
    #pragma unroll
    for (int c = 0; c < 32; ++c) acc += hh[c] * Ws2[c * EMBC + t];
    emb[s * EMBC + t] = acc;
  }
}

// ---------------- B[s,i,o] = sum_j emb[s,j] * Wa1[i*16+j, o] ----------------
__global__ __launch_bounds__(256) void k_B(const float* __restrict__ Wa1,
                                           const float* __restrict__ emb,
                                           float* __restrict__ B) {
  const int i = blockIdx.x;   // 0..215
  const int o = threadIdx.x;  // 0..255
  __shared__ float s_emb[NELEMC * EMBC];
  for (int idx = o; idx < NELEMC * EMBC; idx += 256) s_emb[idx] = emb[idx];
  float w[EMBC];
  #pragma unroll
  for (int j = 0; j < EMBC; ++j) w[j] = Wa1[(size_t)(i * EMBC + j) * H1C + o];
  __syncthreads();
  for (int s = 0; s < NELEMC; ++s) {
    float acc = 0.0f;
    #pragma unroll
    for (int j = 0; j < EMBC; ++j) acc += s_emb[s * EMBC + j] * w[j];
    B[((size_t)s * NFEAT + i) * H1C + o] = acc;
  }
}

// ---------------- counting sort of atoms by species ----------------
__global__ void k_sort(const int* __restrict__ sp, int* __restrict__ order, int nat) {
  __shared__ int cnt[NELEMC];
  __shared__ int off[NELEMC];
  int t = threadIdx.x;
  for (int i = t; i < NELEMC; i += 256) cnt[i] = 0;
  __syncthreads();
  for (int a = t; a < nat; a += 256) atomicAdd(&cnt[sp[a]], 1);
  __syncthreads();
  if (t == 0) { int run = 0; for (int s = 0; s < NELEMC; ++s) { off[s] = run; run += cnt[s]; } }
  __syncthreads();
  for (int a = t; a < nat; a += 256) { int pos = atomicAdd(&off[sp[a]], 1); order[pos] = a; }
}

// ---------------- per-atom MLP: feat@B[s] -> silu -> @Wa2 -> silu -> .Wa3 ----
__global__ __launch_bounds__(256) void k_mlp(
    const float* __restrict__ feat, const float* __restrict__ B,
    const float* __restrict__ ba1, const float* __restrict__ Wa2,
    const float* __restrict__ ba2, const float* __restrict__ Wa3,
    const float* __restrict__ ba3, const int* __restrict__ order,
    const int* __restrict__ sp, float* __restrict__ e_out, int nat) {
  const int nb = gridDim.x;
  int rank = blockIdx.x;
  if ((nb & 7) == 0) rank = (blockIdx.x & 7) * (nb >> 3) + (blockIdx.x >> 3);
  const int a = order[rank];
  const int s = sp[a];
  const int t = threadIdx.x;
  __shared__ float s_feat[NFEAT];
  __shared__ float s_h1[H1C];
  __shared__ float s_red[H2C];
  if (t < NFEAT) s_feat[t] = feat[(size_t)a * NFEAT + t];
  __syncthreads();
  {
    double a0 = (double)ba1[t], a1 = 0.0;
    const float* Bp = B + (size_t)s * NFEAT * H1C + t;
    #pragma unroll 4
    for (int i = 0; i < NFEAT; i += 2) {
      a0 += (double)s_feat[i] * (double)Bp[(size_t)i * H1C];
      a1 += (double)s_feat[i + 1] * (double)Bp[(size_t)(i + 1) * H1C];
    }
    s_h1[t] = silu((float)(a0 + a1));
  }
  __syncthreads();
  if (t < H2C) {
    double a0 = (double)ba2[t], a1 = 0.0;
    #pragma unroll 4
    for (int j = 0; j < H1C; j += 2) {
      a0 += (double)s_h1[j] * (double)Wa2[j * H2C + t];
      a1 += (double)s_h1[j + 1] * (double)Wa2[(j + 1) * H2C + t];
    }
    float h2 = silu((float)(a0 + a1));
    s_red[t] = h2 * Wa3[t];
  }
  __syncthreads();
  if (t < 64) {
    float v = s_red[t] + s_red[t + 64];
    for (int o = 32; o; o >>= 1) v += __shfl_down(v, o, 64);
    if (t == 0) e_out[a] = v + ba3[0];
  }
}

// ---------------- final sum (double) ----------------
__global__ void k_reduce(const float* __restrict__ e_in, float* __restrict__ out, int nat) {
  int t = threadIdx.x;
  double acc = 0.0;
  for (int i = t; i < nat; i += 256) acc += (double)e_in[i];
  for (int o = 32; o; o >>= 1) acc += __shfl_down(acc, o, 64);
  __shared__ double s_par[4];
  if ((t & 63) == 0) s_par[t >> 6] = acc;
  __syncthreads();
  if (t == 0) out[0] = (float)(s_par[0] + s_par[1] + s_par[2] + s_par[3]);
}

extern "C" void kernel_launch(void* const* d_in, const int* in_sizes, int n_in,
                              void* d_out, int out_size, void* d_ws, size_t ws_size,
                              hipStream_t stream) {
  const float* rij = (const float*)d_in[0];
  const float* Wr1 = (const float*)d_in[1];
  const float* br1 = (const float*)d_in[2];
  const float* Wr2 = (const float*)d_in[3];
  const float* br2 = (const float*)d_in[4];
  const float* Ws1 = (const float*)d_in[5];
  const float* bs1 = (const float*)d_in[6];
  const float* Ws2 = (const float*)d_in[7];
  const float* bs2 = (const float*)d_in[8];
  const float* Wa1 = (const float*)d_in[9];
  const float* ba1 = (const float*)d_in[10];
  const float* Wa2 = (const float*)d_in[11];
  const float* ba2 = (const float*)d_in[12];
  const float* Wa3 = (const float*)d_in[13];
  const float* ba3 = (const float*)d_in[14];
  const int* fai = (const int*)d_in[15];
  const int* spc = (const int*)d_in[16];

  const int E = in_sizes[0] / 3;
  const int nat = in_sizes[16];

  float* ws = (float*)d_ws;
  size_t off = 0;
  float* radial = ws + off; off += (size_t)E * 120;          // transposed float4 [30][E]
  float* feat = ws + off;   off += (size_t)nat * NFEAT;
  float* emb = ws + off;    off += (size_t)NELEMC * EMBC;
  float* Bm = ws + off;     off += (size_t)NELEMC * NFEAT * H1C;
  float* e_ws = ws + off;   off += (size_t)nat;
  int* order = (int*)(ws + off);

  k_edge<<<(E + 63) / 64, 256, 0, stream>>>(rij, Wr1, br1, Wr2, br2, (float4*)radial, E);
  k_atom<<<nat, 256, 0, stream>>>(rij, (const float4*)radial, fai, feat, E);
  k_emb<<<NELEMC, 64, 0, stream>>>(Ws1, bs1, Ws2, bs2, emb);
  k_B<<<NFEAT, 256, 0, stream>>>(Wa1, emb, Bm);
  k_sort<<<1, 256, 0, stream>>>(spc, order, nat);
  k_mlp<<<nat, 256, 0, stream>>>(feat, Bm, ba1, Wa2, ba2, Wa3, ba3, order, spc, e_ws, nat);
  k_reduce<<<1, 256, 0, stream>>>(e_ws, (float*)d_out, nat);
}

// Round 4
// 231.277 us; speedup vs baseline: 1.0594x; 1.0594x over previous
//
#include <hip/hip_runtime.h>
#include <math.h>

#define KTOT 69
#define NRADC 24
#define NFEAT 216
#define NELEMC 94
#define EMBC 16
#define H1C 256
#define H2C 128
#define CE 16          // edges per chunk in k_atom
#define EPR 20         // padded edge stride for s_radT rows
#define KGN 18         // padded k-groups (72 padded k / 4)
#define GSTR 84        // s_gijT kg-stride
#define GISTR 76       // s_gi rad-stride

// ---- static lxlylz enumeration (z=1..4 concatenated; real k = 0..68) ----
__device__ __constant__ int c_lx[KTOT] = {
  0,0,0,1,
  0,0,0,1,0,0,0,1,1,2,
  0,0,0,1,0,0,0,1,1,2,0,0,0,0,1,1,1,2,2,3,
  0,0,0,1,0,0,0,1,1,2,0,0,0,0,1,1,1,2,2,3,0,0,0,0,0,1,1,1,1,2,2,2,3,3,4};
__device__ __constant__ int c_ly[KTOT] = {
  0,0,1,0,
  0,0,1,0,0,1,2,0,1,0,
  0,0,1,0,0,1,2,0,1,0,0,1,2,3,0,1,2,0,1,0,
  0,0,1,0,0,1,2,0,1,0,0,1,2,3,0,1,2,0,1,0,0,1,2,3,4,0,1,2,3,0,1,2,0,1,0};
__device__ __constant__ int c_lz[KTOT] = {
  0,1,0,0,
  0,1,0,0,2,1,0,1,0,0,
  0,1,0,0,2,1,0,1,0,0,3,2,1,0,2,1,0,1,0,0,
  0,1,0,0,2,1,0,1,0,0,3,2,1,0,2,1,0,1,0,0,4,3,2,1,0,3,2,1,0,2,1,0,1,0,0};
__device__ __constant__ float c_fn[KTOT] = {
  1,1,1,1,
  1,2,2,2,1,2,1,2,2,1,
  1,3,3,3,3,6,3,6,6,3,1,3,3,1,3,6,3,3,3,1,
  1,4,4,4,6,12,6,12,12,6,4,12,12,4,12,24,12,12,12,4,
  1,4,6,4,1,4,12,12,4,6,12,6,4,4,1};
__device__ __constant__ float c_lam[KTOT] = {
  1,-1,-1,-1,
  1,-1,-1,-1,1,1,1,1,1,1,
  1,-1,-1,-1,1,1,1,1,1,1,-1,-1,-1,-1,-1,-1,-1,-1,-1,-1,
  1,-1,-1,-1,1,1,1,1,1,1,-1,-1,-1,-1,-1,-1,-1,-1,-1,-1,
  1,1,1,1,1,1,1,1,1,1,1,1,1,1,1};
__device__ __constant__ int c_k0[4] = {0,4,14,34};
__device__ __constant__ int c_kn[4] = {4,10,20,35};
__device__ __constant__ float c_zn[4] = {1.0f, 0.5f, 0.25f, 0.125f};
// z per padded k-group (padded k layout: z0 rows 0-3, z1 4-15, z2 16-35, z3 36-71)
__device__ __constant__ int c_zidg[KGN] = {0, 1,1,1, 2,2,2,2,2, 3,3,3,3,3,3,3,3,3};

__device__ __forceinline__ float silu(float x) { return x / (1.0f + expf(-x)); }
__device__ __forceinline__ float4 silu4(float4 v) {
  v.x = silu(v.x); v.y = silu(v.y); v.z = silu(v.z); v.w = silu(v.w); return v;
}
__device__ __forceinline__ void fma4(float4& a, float s, const float4 w) {
  a.x += s * w.x; a.y += s * w.y; a.z += s * w.z; a.w += s * w.w;
}
__device__ __forceinline__ void fma44(float4& a, const float4 x, const float4 y) {
  a.x += x.x * y.x; a.y += x.y * y.y; a.z += x.z * y.z; a.w += x.w * y.w;
}
__device__ __forceinline__ float hsum4(const float4 v) { return (v.x + v.y) + (v.z + v.w); }
__device__ __forceinline__ float powsel(int l, float p, float p2, float p3, float p4) {
  float v = 1.0f;
  v = l >= 1 ? p : v;
  v = l >= 2 ? p2 : v;
  v = l >= 3 ? p3 : v;
  v = l >= 4 ? p4 : v;
  return v;
}

// ---------------- Kernel 0: segment bounds from sorted fai ----------------
// bounds[a] = first edge index e with fai[e] >= a; bounds[nat] = E.
__global__ void k_bounds(const int* __restrict__ fai, int* __restrict__ bounds,
                         int E, int nat) {
  int e = blockIdx.x * blockDim.x + threadIdx.x;
  if (e >= E) return;
  int f = fai[e];
  int fp = (e == 0) ? -1 : fai[e - 1];
  for (int a = fp + 1; a <= f; ++a) bounds[a] = e;
  if (e == E - 1)
    for (int a = f + 1; a <= nat; ++a) bounds[a] = E;
}

// ---------------- Kernel 1: per-edge radial MLP (edge x ogroup parallel) ----
// radial output TRANSPOSED as float4: radial4[o4 * E + e], o4 in [0,30)
template <int NQ>
__device__ __forceinline__ void edge_layer2(
    const float* __restrict__ s_h, const float* __restrict__ Wr2,
    const float* __restrict__ br2, float4* __restrict__ radial4,
    int e, int og, int eg, int E) {
  float4 acc[NQ];
  const float4* b2 = (const float4*)(br2 + og * 32);
  #pragma unroll
  for (int q = 0; q < NQ; ++q) acc[q] = b2[q];
  #pragma unroll 2
  for (int j = 0; j < 64; ++j) {
    float hv = s_h[e * 65 + j];
    const float4* w = (const float4*)(Wr2 + j * 120 + og * 32);
    #pragma unroll
    for (int q = 0; q < NQ; ++q) fma4(acc[q], hv, w[q]);
  }
  if (eg < E) {
    #pragma unroll
    for (int q = 0; q < NQ; ++q)
      radial4[(size_t)(og * 8 + q) * E + eg] = silu4(acc[q]);
  }
}

__global__ __launch_bounds__(256) void k_edge(
    const float* __restrict__ rij,
    const float* __restrict__ Wr1, const float* __restrict__ br1,
    const float* __restrict__ Wr2, const float* __restrict__ br2,
    float4* __restrict__ radial4, int E) {
  __shared__ float s_bas[64 * 25];
  __shared__ float s_h[64 * 65];
  const int tid = threadIdx.x;
  const int e = tid & 63;
  const int og = __builtin_amdgcn_readfirstlane(tid >> 6);
  const int eg = blockIdx.x * 64 + e;

  {
    float x = 0.0f, y = 0.0f, z = 0.0f;
    if (eg < E) { x = rij[eg * 3 + 0]; y = rij[eg * 3 + 1]; z = rij[eg * 3 + 2]; }
    float r = sqrtf(x * x + y * y + z * z);
    float rc = fminf(r, 6.0f);
    float fcv = (eg < E)
        ? 0.5f * (cosf(3.14159265358979323846f * rc * (1.0f / 6.0f)) + 1.0f)
        : 0.0f;
    #pragma unroll
    for (int t = 0; t < 6; ++t) {
      int m = og * 6 + t;
      float d = r - (6.0f / 23.0f) * (float)m;
      s_bas[e * 25 + m] = expf(-8.0f * d * d) * fcv;
    }
  }
  __syncthreads();

  {
    const float4* b1 = (const float4*)(br1 + og * 16);
    float4 acc[4] = {b1[0], b1[1], b1[2], b1[3]};
    #pragma unroll 4
    for (int m = 0; m < NRADC; ++m) {
      float b = s_bas[e * 25 + m];
      const float4* w = (const float4*)(Wr1 + m * 64 + og * 16);
      #pragma unroll
      for (int q = 0; q < 4; ++q) fma4(acc[q], b, w[q]);
    }
    #pragma unroll
    for (int q = 0; q < 4; ++q) {
      float4 v = silu4(acc[q]);
      float* dst = &s_h[e * 65 + og * 16 + 4 * q];
      dst[0] = v.x; dst[1] = v.y; dst[2] = v.z; dst[3] = v.w;
    }
  }
  __syncthreads();

  if (og < 3) edge_layer2<8>(s_h, Wr2, br2, radial4, e, og, eg, E);
  else        edge_layer2<6>(s_h, Wr2, br2, radial4, e, og, eg, E);
}

// ---------------- Kernel 2: per-atom angular accumulation -> feat[216] ----
// Register-tiled outer product; NO occupancy bound (R2's ,4 caused acc spill).
__global__ __launch_bounds__(256) void k_atom(
    const float* __restrict__ rij,
    const float4* __restrict__ radial4,
    const int* __restrict__ bounds,
    float* __restrict__ feat, int E) {
  const int a = blockIdx.x;
  const int tid = threadIdx.x;
  __shared__ __align__(16) float s_radT[120 * EPR];   // [comp][edge]
  __shared__ __align__(16) float s_gijT[KGN * GSTR];  // [kgroup][j*20+edge]
  __shared__ __align__(16) float s_gi[NRADC * GISTR]; // [rad][padded k]
  __shared__ float s_feat[NFEAT];

  const int start = bounds[a];
  const int end = bounds[a + 1];

  // role assignment
  const bool is_tile = tid < 216;
  const int eh = is_tile ? (tid / 108) : 0;
  const int tile = is_tile ? (tid % 108) : 0;
  const int rg = tile % 6;
  const int kg = tile / 6;
  const int zz = c_zidg[kg];
  const int comp0 = rg * 20 + 1 + zz;   // (rg*4)*5 + 1 + z
  const bool is_2b = (tid >= 216 && tid < 240);
  const int rad2b = tid - 216;

  // zero the fake padded-k rows (prow 14,15,71), cols 0..19
  if (tid < 60) {
    int rr = tid / EPR, e = tid % EPR;
    int fkg = rr < 2 ? 3 : 17;
    int fj = rr < 2 ? 2 + rr : 3;
    s_gijT[fkg * GSTR + fj * EPR + e] = 0.0f;
  }

  float4 acc[4][4];
  #pragma unroll
  for (int i = 0; i < 4; ++i)
    #pragma unroll
    for (int j = 0; j < 4; ++j) acc[i][j] = make_float4(0, 0, 0, 0);
  float4 acc2b = make_float4(0, 0, 0, 0);

  for (int c0 = start; c0 < end; c0 += CE) {
    const int ne = min(CE, end - c0);
    // ---- stage radial transposed: [comp][e], zero for e >= ne ----
    for (int idx = tid; idx < 30 * CE; idx += 256) {
      int o4 = idx >> 4;
      int e = idx & 15;
      float4 v = make_float4(0, 0, 0, 0);
      if (e < ne) v = radial4[(size_t)o4 * E + (c0 + e)];
      int c = o4 * 4;
      s_radT[(c + 0) * EPR + e] = v.x;
      s_radT[(c + 1) * EPR + e] = v.y;
      s_radT[(c + 2) * EPR + e] = v.z;
      s_radT[(c + 3) * EPR + e] = v.w;
    }
    // ---- gij in registers -> s_gijT[kg][j*20+e] ----
    {
      int e = tid >> 4, sub = tid & 15;
      int eg = c0 + e;
      bool ev = e < ne;
      float x = 1.0f, y = 0.0f, z3 = 0.0f;
      if (ev) { x = rij[eg * 3 + 0]; y = rij[eg * 3 + 1]; z3 = rij[eg * 3 + 2]; }
      float r = sqrtf(x * x + y * y + z3 * z3);
      float inv = 1.0f / r;
      float px = x * inv + 1e-12f, py = y * inv + 1e-12f, pz = z3 * inv + 1e-12f;
      float p2x = px * px, p3x = p2x * px, p4x = p2x * p2x;
      float p2y = py * py, p3y = p2y * py, p4y = p2y * p2y;
      float p2z = pz * pz, p3z = p2z * pz, p4z = p2z * p2z;
      int kstart = sub < 5 ? sub * 5 : 25 + (sub - 5) * 4;
      int kcnt = sub < 5 ? 5 : 4;
      for (int t = 0; t < kcnt; ++t) {
        int k = kstart + t;
        float g = powsel(c_lx[k], px, p2x, p3x, p4x) *
                  powsel(c_ly[k], py, p2y, p3y, p4y) *
                  powsel(c_lz[k], pz, p2z, p3z, p4z) * c_fn[k];
        if (!ev) g = 0.0f;
        int prow = k + (k < 14 ? 0 : 2);
        s_gijT[(prow >> 2) * GSTR + (prow & 3) * EPR + e] = g;
      }
    }
    __syncthreads();
    // ---- tiled outer-product accumulate over 4-edge vectors ----
    if (is_tile) {
      #pragma unroll
      for (int s = 0; s < 2; ++s) {
        int e0 = eh * 8 + s * 4;
        float4 gg[4];
        #pragma unroll
        for (int j = 0; j < 4; ++j)
          gg[j] = *(const float4*)&s_gijT[kg * GSTR + j * EPR + e0];
        #pragma unroll
        for (int i = 0; i < 4; ++i) {
          float4 rr = *(const float4*)&s_radT[(comp0 + 5 * i) * EPR + e0];
          #pragma unroll
          for (int j = 0; j < 4; ++j) fma44(acc[i][j], rr, gg[j]);
        }
      }
    }
    if (is_2b) {
      #pragma unroll
      for (int e0 = 0; e0 < 16; e0 += 4) {
        float4 v = *(const float4*)&s_radT[(rad2b * 5) * EPR + e0];
        acc2b.x += v.x; acc2b.y += v.y; acc2b.z += v.z; acc2b.w += v.w;
      }
    }
    __syncthreads();
  }

  // ---- epilogue: horizontal sums -> s_gi, then cross-eh add ----
  float4 hs[4];
  #pragma unroll
  for (int i = 0; i < 4; ++i)
    hs[i] = make_float4(hsum4(acc[i][0]), hsum4(acc[i][1]),
                        hsum4(acc[i][2]), hsum4(acc[i][3]));
  if (is_tile && eh == 0) {
    #pragma unroll
    for (int i = 0; i < 4; ++i)
      *(float4*)&s_gi[(rg * 4 + i) * GISTR + kg * 4] = hs[i];
  }
  if (is_2b) s_feat[rad2b] = hsum4(acc2b);
  __syncthreads();
  if (is_tile && eh == 1) {
    #pragma unroll
    for (int i = 0; i < 4; ++i) {
      float4 v = *(const float4*)&s_gi[(rg * 4 + i) * GISTR + kg * 4];
      v.x += hs[i].x; v.y += hs[i].y; v.z += hs[i].z; v.w += hs[i].w;
      *(float4*)&s_gi[(rg * 4 + i) * GISTR + kg * 4] = v;
    }
  }
  __syncthreads();

  // ---- feat: sum g^2 (+/- lambda) over real ks ----
  if (tid < 192) {
    int zb = tid / NRADC;
    int rad = tid - zb * NRADC;
    int z = zb >> 1;
    bool neg = zb & 1;
    int k0 = c_k0[z], kn = c_kn[z];
    float s = 0.0f;
    for (int k = k0; k < k0 + kn; ++k) {
      int prow = k + (k < 14 ? 0 : 2);
      float g = s_gi[rad * GISTR + prow];
      float g2 = g * g;
      s += neg ? g2 * c_lam[k] : g2;
    }
    s_feat[NRADC + zb * NRADC + rad] = s * c_zn[z];
  }
  __syncthreads();
  if (tid < NFEAT) feat[(size_t)a * NFEAT + tid] = s_feat[tid];
}

// ---------------- species embedding (94 x 16) ----------------
__global__ void k_emb(const float* __restrict__ Ws1, const float* __restrict__ bs1,
                      const float* __restrict__ Ws2, const float* __restrict__ bs2,
                      float* __restrict__ emb) {
  int s = blockIdx.x, t = threadIdx.x;
  __shared__ float hh[32];
  if (t < 32) hh[t] = silu(Ws1[s * 32 + t] + bs1[t]);
  __syncthreads();
  if (t < EMBC) {
    float acc = bs2[t];
    #pragma unroll
    for (int c = 0; c < 32; ++c) acc += hh[c] * Ws2[c * EMBC + t];
    emb[s * EMBC + t] = acc;
  }
}

// ---------------- B[s,i,o] = sum_j emb[s,j] * Wa1[i*16+j, o] ----------------
__global__ __launch_bounds__(256) void k_B(const float* __restrict__ Wa1,
                                           const float* __restrict__ emb,
                                           float* __restrict__ B) {
  const int i = blockIdx.x;   // 0..215
  const int o = threadIdx.x;  // 0..255
  __shared__ float s_emb[NELEMC * EMBC];
  for (int idx = o; idx < NELEMC * EMBC; idx += 256) s_emb[idx] = emb[idx];
  float w[EMBC];
  #pragma unroll
  for (int j = 0; j < EMBC; ++j) w[j] = Wa1[(size_t)(i * EMBC + j) * H1C + o];
  __syncthreads();
  for (int s = 0; s < NELEMC; ++s) {
    float acc = 0.0f;
    #pragma unroll
    for (int j = 0; j < EMBC; ++j) acc += s_emb[s * EMBC + j] * w[j];
    B[((size_t)s * NFEAT + i) * H1C + o] = acc;
  }
}

// ---------------- counting sort of atoms by species ----------------
__global__ void k_sort(const int* __restrict__ sp, int* __restrict__ order, int nat) {
  __shared__ int cnt[NELEMC];
  __shared__ int off[NELEMC];
  int t = threadIdx.x;
  for (int i = t; i < NELEMC; i += 256) cnt[i] = 0;
  __syncthreads();
  for (int a = t; a < nat; a += 256) atomicAdd(&cnt[sp[a]], 1);
  __syncthreads();
  if (t == 0) { int run = 0; for (int s = 0; s < NELEMC; ++s) { off[s] = run; run += cnt[s]; } }
  __syncthreads();
  for (int a = t; a < nat; a += 256) { int pos = atomicAdd(&off[sp[a]], 1); order[pos] = a; }
}

// ---------------- per-atom MLP: feat@B[s] -> silu -> @Wa2 -> silu -> .Wa3 ----
__global__ __launch_bounds__(256) void k_mlp(
    const float* __restrict__ feat, const float* __restrict__ B,
    const float* __restrict__ ba1, const float* __restrict__ Wa2,
    const float* __restrict__ ba2, const float* __restrict__ Wa3,
    const float* __restrict__ ba3, const int* __restrict__ order,
    const int* __restrict__ sp, float* __restrict__ e_out, int nat) {
  const int nb = gridDim.x;
  int rank = blockIdx.x;
  if ((nb & 7) == 0) rank = (blockIdx.x & 7) * (nb >> 3) + (blockIdx.x >> 3);
  const int a = order[rank];
  const int s = sp[a];
  const int t = threadIdx.x;
  __shared__ float s_feat[NFEAT];
  __shared__ float s_h1[H1C];
  __shared__ float s_red[H2C];
  if (t < NFEAT) s_feat[t] = feat[(size_t)a * NFEAT + t];
  __syncthreads();
  {
    double a0 = (double)ba1[t], a1 = 0.0;
    const float* Bp = B + (size_t)s * NFEAT * H1C + t;
    #pragma unroll 4
    for (int i = 0; i < NFEAT; i += 2) {
      a0 += (double)s_feat[i] * (double)Bp[(size_t)i * H1C];
      a1 += (double)s_feat[i + 1] * (double)Bp[(size_t)(i + 1) * H1C];
    }
    s_h1[t] = silu((float)(a0 + a1));
  }
  __syncthreads();
  if (t < H2C) {
    double a0 = (double)ba2[t], a1 = 0.0;
    #pragma unroll 4
    for (int j = 0; j < H1C; j += 2) {
      a0 += (double)s_h1[j] * (double)Wa2[j * H2C + t];
      a1 += (double)s_h1[j + 1] * (double)Wa2[(j + 1) * H2C + t];
    }
    float h2 = silu((float)(a0 + a1));
    s_red[t] = h2 * Wa3[t];
  }
  __syncthreads();
  if (t < 64) {
    float v = s_red[t] + s_red[t + 64];
    for (int o = 32; o; o >>= 1) v += __shfl_down(v, o, 64);
    if (t == 0) e_out[a] = v + ba3[0];
  }
}

// ---------------- final sum (double) ----------------
__global__ void k_reduce(const float* __restrict__ e_in, float* __restrict__ out, int nat) {
  int t = threadIdx.x;
  double acc = 0.0;
  for (int i = t; i < nat; i += 256) acc += (double)e_in[i];
  for (int o = 32; o; o >>= 1) acc += __shfl_down(acc, o, 64);
  __shared__ double s_par[4];
  if ((t & 63) == 0) s_par[t >> 6] = acc;
  __syncthreads();
  if (t == 0) out[0] = (float)(s_par[0] + s_par[1] + s_par[2] + s_par[3]);
}

extern "C" void kernel_launch(void* const* d_in, const int* in_sizes, int n_in,
                              void* d_out, int out_size, void* d_ws, size_t ws_size,
                              hipStream_t stream) {
  const float* rij = (const float*)d_in[0];
  const float* Wr1 = (const float*)d_in[1];
  const float* br1 = (const float*)d_in[2];
  const float* Wr2 = (const float*)d_in[3];
  const float* br2 = (const float*)d_in[4];
  const float* Ws1 = (const float*)d_in[5];
  const float* bs1 = (const float*)d_in[6];
  const float* Ws2 = (const float*)d_in[7];
  const float* bs2 = (const float*)d_in[8];
  const float* Wa1 = (const float*)d_in[9];
  const float* ba1 = (const float*)d_in[10];
  const float* Wa2 = (const float*)d_in[11];
  const float* ba2 = (const float*)d_in[12];
  const float* Wa3 = (const float*)d_in[13];
  const float* ba3 = (const float*)d_in[14];
  const int* fai = (const int*)d_in[15];
  const int* spc = (const int*)d_in[16];

  const int E = in_sizes[0] / 3;
  const int nat = in_sizes[16];

  float* ws = (float*)d_ws;
  size_t off = 0;
  float* radial = ws + off; off += (size_t)E * 120;          // transposed float4 [30][E]
  float* feat = ws + off;   off += (size_t)nat * NFEAT;
  float* emb = ws + off;    off += (size_t)NELEMC * EMBC;
  float* Bm = ws + off;     off += (size_t)NELEMC * NFEAT * H1C;
  float* e_ws = ws + off;   off += (size_t)nat;
  int* order = (int*)(ws + off); off += (size_t)nat;
  int* bounds = (int*)(ws + off);

  k_bounds<<<(E + 255) / 256, 256, 0, stream>>>(fai, bounds, E, nat);
  k_edge<<<(E + 63) / 64, 256, 0, stream>>>(rij, Wr1, br1, Wr2, br2, (float4*)radial, E);
  k_atom<<<nat, 256, 0, stream>>>(rij, (const float4*)radial, bounds, feat, E);
  k_emb<<<NELEMC, 64, 0, stream>>>(Ws1, bs1, Ws2, bs2, emb);
  k_B<<<NFEAT, 256, 0, stream>>>(Wa1, emb, Bm);
  k_sort<<<1, 256, 0, stream>>>(spc, order, nat);
  k_mlp<<<nat, 256, 0, stream>>>(feat, Bm, ba1, Wa2, ba2, Wa3, ba3, order, spc, e_ws, nat);
  k_reduce<<<1, 256, 0, stream>>>(e_ws, (float*)d_out, nat);
}